// Round 13
// baseline (217.306 us; speedup 1.0000x reference)
//
#include <hip/hip_runtime.h>
#include <stdint.h>

// Problem constants
#define BB   2048
#define DIN  2048
#define UU   1024
#define KF   49
#define GM   2048         // GEMM M = batch
#define GK   3072         // GEMM K = UU + DIN
#define GN   5120         // GEMM N = 5*UU

// GEMM block geometry: 128 rows x 32 ucols x 5 gates, 256 threads (4 waves 2x2)
#define BKS  32           // K per step (96 steps)
#define SZB  18432        // bytes per LDS buffer: A 8KB + B 10KB; 3 buffers = 54KB
                          // -> 2 blocks/CU (the R13 lever: cross-block overlap)

typedef __bf16  bf16x8 __attribute__((ext_vector_type(8)));
typedef float   f32x4  __attribute__((ext_vector_type(4)));

#define VL(dst, ptr) asm volatile("global_load_dwordx4 %0, %1, off" \
                                  : "=v"(dst) : "v"(ptr) : "memory")

static __device__ __forceinline__ unsigned short f2bf(float f) {
    union { float f; unsigned u; } x; x.f = f;
    unsigned u = x.u;
    unsigned r = (u + 0x7fffu + ((u >> 16) & 1u)) >> 16;   // RNE
    return (unsigned short)r;
}

// ---------------------------------------------------------------------------
// Kernel 1: prep = buildA (blocks [0,6144)) + buildW transpose (rest)
//   A[b][k]  = bf16([h_tm | inputs])                             [GM][GK]
//   Wt[n][k] = bf16(k<UU ? W_gates[k][n] : U_gates[k-UU][n])     [GN][GK]
// ---------------------------------------------------------------------------
__global__ void prep(const float* __restrict__ h, const float* __restrict__ x,
                     const float* __restrict__ Wg, const float* __restrict__ Ug,
                     unsigned short* __restrict__ A, unsigned short* __restrict__ Wt) {
    __shared__ float t[32][36];
    if (blockIdx.x < 6144) {
        int idx = blockIdx.x * 256 + threadIdx.x;    // one thread = 4 elems
        int b = idx / (GK / 4);
        int k = (idx % (GK / 4)) * 4;
        float4 v;
        if (k < UU) v = *(const float4*)(h + (size_t)b * UU + k);
        else        v = *(const float4*)(x + (size_t)b * DIN + (k - UU));
        ushort4 o;
        o.x = f2bf(v.x); o.y = f2bf(v.y); o.z = f2bf(v.z); o.w = f2bf(v.w);
        *(ushort4*)(A + (size_t)idx * 4) = o;
    } else {
        int bid2 = blockIdx.x - 6144;                // 32x32 transpose tiles
        int k0 = (bid2 % (GK / 32)) * 32;
        int n0 = (bid2 / (GK / 32)) * 32;
        int r  = threadIdx.x >> 3;                   // 0..31
        int cq = threadIdx.x & 7;                    // 0..7  (x4 floats)
        int k = k0 + r;
        const float* src = (k < UU) ? (Wg + (size_t)k * GN) : (Ug + (size_t)(k - UU) * GN);
        *(float4*)&t[r][cq * 4] = *(const float4*)(src + n0 + cq * 4);
        __syncthreads();
        ushort4 o;
        o.x = f2bf(t[cq * 4 + 0][r]);
        o.y = f2bf(t[cq * 4 + 1][r]);
        o.z = f2bf(t[cq * 4 + 2][r]);
        o.w = f2bf(t[cq * 4 + 3][r]);
        *(ushort4*)(Wt + (size_t)(n0 + r) * GK + k0 + cq * 4) = o;
    }
}

// ---------------------------------------------------------------------------
// Kernel 2: fused 5-gate GEMM + v_seq reduction + LSTM tail.
// R6's PROVEN 3-buffer counted-vmcnt schedule, re-sized for 2 blocks/CU:
//   256 threads (4 waves 2x2), tile 128 rows x 32 ucols x 5 gates, 54KB LDS.
//   grid = 512 = exactly 2 blocks/CU: two INDEPENDENT barrier domains per CU
//   so one block's drain overlaps the other's MFMA/ds_read (m114/m102 mechanism
//   -- the single-block-per-CU serialization was R4-R12's real limiter).
// Per step t: consume V(t) -> STAGE(t+2) (5 uniform gload_lds) -> VL V(t+2)
//   -> COMPUTE(t) -> vmcnt(7) [drains stage(t+1) + VL(t+1-consumable); keeps
//   stage(t+2)5 + VL2] -> s_barrier -> sched_barrier(0).
// XCD-chunked bijective swizzle (512 = 8 x 64): same-XCD blocks share A-panels.
// ---------------------------------------------------------------------------
__global__ __launch_bounds__(256, 2) void gemm_fused(
        const unsigned short* __restrict__ A, const unsigned short* __restrict__ Wt,
        const float* __restrict__ m_tm, const float* __restrict__ bg,
        const float* __restrict__ v_seq, float* __restrict__ out) {
    __shared__ __align__(16) char lds[3 * SZB];      // 55,296 B -> 2 blocks/CU

    const int tid  = threadIdx.x;
    const int lane = tid & 63;
    const int wave = tid >> 6;          // 0..3
    const int wr = wave >> 1, wc = wave & 1;
    // XCD swizzle: bid%8 = XCD; chunk of 64 consecutive swz per XCD
    const int swz = (blockIdx.x & 7) * 64 + (blockIdx.x >> 3);
    const int brow  = (swz >> 5) * 128;              // 16 row-tiles
    const int ucol0 = (swz & 31) * 32;               // 32 ucol-tiles

    f32x4 acc[4][5];
#pragma unroll
    for (int m = 0; m < 4; m++)
#pragma unroll
        for (int g = 0; g < 5; g++) acc[m][g] = (f32x4){0.f, 0.f, 0.f, 0.f};

    // staging: 1152 chunks of 16B per K-step (A 512, B 640), 5 uniform rounds
    // (round 4 duplicated across thread halves -> identical bytes, uniform count)
    const unsigned short* src[5];
    int ldsoff[5];
#pragma unroll
    for (int r = 0; r < 5; ++r) {
        if (r < 2) {
            int j = r * 256 + tid;
            src[r] = A + (size_t)(brow + (j >> 2)) * GK + (j & 3) * 8;
            ldsoff[r] = j * 16;
        } else {
            int j2 = (r < 4) ? (r - 2) * 256 + tid : 512 + (tid & 127);
            int g = j2 >> 7;                         // rB = j2>>2 = g*32+nn
            int nn = (j2 >> 2) & 31;
            int c = j2 & 3;
            src[r] = Wt + ((size_t)g * UU + ucol0 + nn) * GK + c * 8;
            ldsoff[r] = 8192 + j2 * 16;
        }
    }

    // fragment read offsets (R2-proven layout)
    int aoff[4], boff[5];
#pragma unroll
    for (int m = 0; m < 4; m++)
        aoff[m] = (wr * 64 + m * 16 + (lane & 15)) * 64 + (lane >> 4) * 16;
#pragma unroll
    for (int g = 0; g < 5; g++)
        boff[g] = 8192 + (g * 32 + wc * 16 + (lane & 15)) * 64 + (lane >> 4) * 16;

    auto STAGE = [&](int kstep, int bufb) {
        const int ko = kstep * BKS;
#pragma unroll
        for (int r = 0; r < 5; ++r)
            __builtin_amdgcn_global_load_lds(
                (const __attribute__((address_space(1))) void*)(src[r] + ko),
                (__attribute__((address_space(3))) void*)(lds + bufb + ldsoff[r]), 16, 0, 0);
    };
    auto COMPUTE = [&](int bufb) {
        bf16x8 af[4], bfr[5];
#pragma unroll
        for (int m = 0; m < 4; m++) af[m]  = *(const bf16x8*)(lds + bufb + aoff[m]);
#pragma unroll
        for (int g = 0; g < 5; g++) bfr[g] = *(const bf16x8*)(lds + bufb + boff[g]);
#pragma unroll
        for (int m = 0; m < 4; m++)
#pragma unroll
            for (int g = 0; g < 5; g++)
                acc[m][g] = __builtin_amdgcn_mfma_f32_16x16x32_bf16(af[m], bfr[g], acc[m][g], 0, 0, 0);
    };

    // v_seq: thread covers rows {r, r+64} (r = tid>>2), cols c1=(tid&3)*4 and c1+16
    // (VL pairs are 64B-contiguous across lanes 4-aligned groups)
    const float* vpa = v_seq + (size_t)(brow + (tid >> 2)) * (KF * UU) + ucol0 + (tid & 3) * 4;
    const float* vpc = vpa + (size_t)64 * KF * UU;
    f32x4 sa = {0,0,0,0}, sb = {0,0,0,0}, sc = {0,0,0,0}, sd = {0,0,0,0};
    f32x4 XA, XB, YA, YB;               // even-step / odd-step load pairs

    // prologue: S(0)->b0, VL X(k=0), S(1)->b1, VL Y(k=0); vmcnt(7) drains S(0)+X... 
    // (X(k0) consumed at t=0: drained; keeps S(1)+Y)
    STAGE(0, 0);
    VL(XA, vpa);
    VL(XB, vpa + 16);
    STAGE(1, SZB);
    VL(YA, vpc);
    VL(YB, vpc + 16);
    asm volatile("s_waitcnt vmcnt(7)" ::: "memory");
    __builtin_amdgcn_s_barrier();
    __builtin_amdgcn_sched_barrier(0);

    int cb = 0;                                      // (t%3)*SZB
    for (int tp = 0; tp < 47; ++tp) {
        {   // even t=2tp: consume X(k=tp), stage t+2, VL X(k=tp+1)
            sa += XA; sb += XB;
            int sbuf = cb + 2 * SZB; if (sbuf >= 3 * SZB) sbuf -= 3 * SZB;
            STAGE(2 * tp + 2, sbuf);
            VL(XA, vpa + (size_t)(tp + 1) * UU);
            VL(XB, vpa + (size_t)(tp + 1) * UU + 16);
            COMPUTE(cb);
            asm volatile("s_waitcnt vmcnt(7)" ::: "memory");
            __builtin_amdgcn_s_barrier();
            __builtin_amdgcn_sched_barrier(0);
            cb += SZB; if (cb >= 3 * SZB) cb = 0;
        }
        {   // odd t=2tp+1: consume Y(k=tp), stage t+2, VL Y(k=tp+1)
            sc += YA; sd += YB;
            int sbuf = cb + 2 * SZB; if (sbuf >= 3 * SZB) sbuf -= 3 * SZB;
            STAGE(2 * tp + 3, sbuf);
            VL(YA, vpc + (size_t)(tp + 1) * UU);
            VL(YB, vpc + (size_t)(tp + 1) * UU + 16);
            COMPUTE(cb);
            asm volatile("s_waitcnt vmcnt(7)" ::: "memory");
            __builtin_amdgcn_s_barrier();
            __builtin_amdgcn_sched_barrier(0);
            cb += SZB; if (cb >= 3 * SZB) cb = 0;
        }
    }
    // t=94: consume X(k=47); no stage/VL; drain all (Y(k47) still in flight)
    sa += XA; sb += XB;
    COMPUTE(cb);
    asm volatile("s_waitcnt vmcnt(0)" ::: "memory");
    __builtin_amdgcn_s_barrier();
    __builtin_amdgcn_sched_barrier(0);
    cb += SZB; if (cb >= 3 * SZB) cb = 0;
    // t=95: consume Y(k=47)
    sc += YA; sd += YB;
    COMPUTE(cb);

    // leftover v_seq k = 48 (plain loads; pipeline drained)
    {
        sa += *(const f32x4*)(vpa + (size_t)48 * UU);
        sb += *(const f32x4*)(vpa + (size_t)48 * UU + 16);
        sc += *(const f32x4*)(vpc + (size_t)48 * UU);
        sd += *(const f32x4*)(vpc + (size_t)48 * UU + 16);
    }

    // exchange v-sums via LDS: lv[128][36] floats (18KB, reuses buffer 0)
    float* lv = (float*)lds;
    {
        const int r = tid >> 2, c1 = (tid & 3) * 4;
        *(f32x4*)&lv[(size_t)r * 36 + c1]             = sa;
        *(f32x4*)&lv[(size_t)r * 36 + c1 + 16]        = sb;
        *(f32x4*)&lv[(size_t)(r + 64) * 36 + c1]      = sc;
        *(f32x4*)&lv[(size_t)(r + 64) * 36 + c1 + 16] = sd;
    }
    __syncthreads();

    // Epilogue: gates + cell + sentinel + ct, write 3 outputs.
    const int ucol = ucol0 + wc * 16 + (lane & 15);
    const int lcol = wc * 16 + (lane & 15);
    const float b0 = bg[0 * UU + ucol];
    const float b1 = bg[1 * UU + ucol];
    const float b2 = bg[2 * UU + ucol];
    const float b3 = bg[3 * UU + ucol];
    const float b4 = bg[4 * UU + ucol];
    const int lr0 = wr * 64 + ((lane >> 4) << 2);
    float* out0 = out;
    float* out1 = out + (size_t)GM * UU;
    float* out2 = out + 2 * (size_t)GM * UU;
#pragma unroll
    for (int m = 0; m < 4; m++) {
#pragma unroll
        for (int j = 0; j < 4; j++) {
            const int lrow = lr0 + m * 16 + j;
            const int row  = brow + lrow;
            const size_t idx = (size_t)row * UU + ucol;
            const float vs  = lv[(size_t)lrow * 36 + lcol];
            const float mtm = m_tm[idx];
            const float f = acc[m][0][j] + b0;
            const float i = acc[m][1][j] + b1;
            const float o = acc[m][2][j] + b2;
            const float g = acc[m][3][j] + b3;
            const float a = acc[m][4][j] + b4;
            const float ft = 1.f / (1.f + __expf(-f));
            const float it = 1.f / (1.f + __expf(-i));
            const float ot = 1.f / (1.f + __expf(-o));
            const float gt = 1.f / (1.f + __expf(-g));
            const float at = tanhf(a);
            const float mtv = mtm * ft + it * at;
            const float tm  = tanhf(mtv);
            const float ht  = ot * tm;
            const float st  = gt * tm;
            out0[idx] = ht + vs + st;
            out1[idx] = ht;
            out2[idx] = mtv;
        }
    }
}

// ---------------------------------------------------------------------------
extern "C" void kernel_launch(void* const* d_in, const int* in_sizes, int n_in,
                              void* d_out, int out_size, void* d_ws, size_t ws_size,
                              hipStream_t stream) {
    (void)in_sizes; (void)n_in; (void)out_size; (void)ws_size;
    const float* inputs  = (const float*)d_in[0];
    const float* h_tm    = (const float*)d_in[1];
    const float* m_tm    = (const float*)d_in[2];
    const float* v_seq   = (const float*)d_in[3];
    const float* W_gates = (const float*)d_in[4];
    const float* U_gates = (const float*)d_in[5];
    const float* b_gates = (const float*)d_in[6];
    // d_in[7..9] (W_z, U_z, W_h) are dead: softmax over a size-1 axis == 1.

    char* ws = (char*)d_ws;
    unsigned short* Abf = (unsigned short*)ws;                  // 2048*3072*2 = 12,582,912 B
    unsigned short* Wt  = (unsigned short*)(ws + 12582912);     // 5120*3072*2 = 31,457,280 B
    float* out = (float*)d_out;

    hipLaunchKernelGGL(prep, dim3(6144 + (GK / 32) * (GN / 32)), dim3(256), 0, stream,
                       h_tm, inputs, W_gates, U_gates, Abf, Wt);
    hipLaunchKernelGGL(gemm_fused, dim3(512), dim3(256), 0, stream,
                       Abf, Wt, m_tm, b_gates, v_seq, out);
}